// Round 15
// baseline (105.116 us; speedup 1.0000x reference)
//
#include <hip/hip_runtime.h>

// SoftDtwRkdDistance: B=32, T=96, D=128, f32 in, scalar f32 out.
// Split design (r11 csq + dual-problem dp):
//   K0 xn:  row squared-norms (separate kernel; r14's inlining cost +12us).
//   K1 csq: r11-proven: A+B panels in LDS with per-row slot rotation
//           (conflict-free ds_read_b128). C'=(xn_a+xn_b-2*dot)*rg2, diag-major.
//   K2 dp:  ONE WAVE = TWO problems (pr, pr+528) fully interleaved -> 4-way
//           ILP on the latency-bound chain. 4-deep prefetch, 2 shfls/diag
//           per problem, phase-split (B dead d<=63 / d>=129).
//   K3 reduce: means + smooth-L1.
// Fallback: if ws too small for the 38 MB C buffer, run the round-3 fused kernel.

constexpr int TT = 96;
constexpr int DD = 128;
constexpr int BB = 32;
constexpr int NP = BB * BB;               // 1024
constexpr int NPAIR = BB * (BB + 1) / 2;  // 528
constexpr int NPROB = 2 * NPAIR;          // 1056
constexpr int CSZ = TT * TT;              // 9216 floats per problem
constexpr float FINF = 1e10f;
constexpr float LOG2E = 1.4426950408889634f;
constexpr float LN2 = 0.6931471805599453f;

__device__ __forceinline__ int tri_base(int a) {   // pairs with first index < a
  return a * BB - (a * (a - 1)) / 2;
}
__device__ __forceinline__ void tri_decode(int pr, int& a, int& b) {
  a = (int)((65.0f - sqrtf(4225.0f - 8.0f * (float)pr)) * 0.5f);
  while (tri_base(a + 1) <= pr) ++a;
  while (tri_base(a) > pr) --a;
  b = a + (pr - tri_base(a));
}
__device__ __forceinline__ int diag_base(int d) {
  return (d <= 95) ? ((d * (d + 1)) >> 1)
                   : 4656 + (((d - 96) * (287 - d)) >> 1);
}
// softmin in z''-domain, op order matches reference (up, left, diag)
__device__ __forceinline__ float smin2(float u, float lf, float dg) {
  float m = fmaxf(fmaxf(u, lf), dg);
  float s = __builtin_amdgcn_exp2f(u - m) + __builtin_amdgcn_exp2f(lf - m)
          + __builtin_amdgcn_exp2f(dg - m);
  return m + __builtin_amdgcn_logf(s);
}

// K0: row squared-norms xn[2][BB*TT]
__global__ void xn_kernel(const float* __restrict__ xs,
                          const float* __restrict__ xt,
                          float* __restrict__ xn) {
  int idx = blockIdx.x * 256 + threadIdx.x;
  if (idx >= 2 * BB * TT) return;
  int which = idx / (BB * TT);
  int row = idx - which * (BB * TT);
  const float* x = which ? xt : xs;
  const float4* xv = reinterpret_cast<const float4*>(x + (size_t)row * DD);
  float acc = 0.f;
#pragma unroll
  for (int k = 0; k < DD / 4; ++k) {
    float4 v = xv[k];
    acc = fmaf(v.x, v.x, acc);
    acc = fmaf(v.y, v.y, acc);
    acc = fmaf(v.z, v.z, acc);
    acc = fmaf(v.w, v.w, acc);
  }
  xn[idx] = acc;
}

// K1: C' in diag-major global layout. One 256-thread block per (pair, tensor).
// r11-proven: per-row slot-rotated LDS layout (conflict-free reads).
__global__ __launch_bounds__(256)
void csq_kernel(const float* __restrict__ xs,
                const float* __restrict__ xt,
                const float* __restrict__ xn,
                const float* __restrict__ gptr,
                float* __restrict__ Cd) {
  __shared__ __align__(16) float Cs[CSZ];   // staging aliases front (6912 floats)
  __shared__ float xna[TT];
  __shared__ float xnb[TT];

  const int pr = blockIdx.x;
  int a, b;
  tri_decode(pr, a, b);
  const int w = blockIdx.y;
  const float* x = w ? xt : xs;
  const float* xnw = xn + w * (BB * TT);
  const float* xa = x + (size_t)a * TT * DD;
  const float* xb = x + (size_t)b * TT * DD;
  const int tid = threadIdx.x;

  if (tid < TT) {
    xna[tid] = xnw[a * TT + tid];
    xnb[tid] = xnw[b * TT + tid];
  }

  // staged panels: [96 rows][9 float4 slots]; row t's logical k4 block lives
  // at slot (k4 + t/6) & 7 (slot 8 unused pad).
  float4* sa = reinterpret_cast<float4*>(Cs);          // A panel: 864 float4
  float4* sb = sa + TT * 9;                            // B panel: 864 float4

  const int wv = tid >> 6;
  const int lane = tid & 63;
  const int tx = (lane & 7) + (wv & 1) * 8;      // 0..15
  const int ty = (lane >> 3) + (wv >> 1) * 8;    // 0..15
  const int t0 = ty * 6, s0 = tx * 6;

  float acc[6][6];
#pragma unroll
  for (int r = 0; r < 6; ++r)
#pragma unroll
    for (int c = 0; c < 6; ++c) acc[r][c] = 0.f;

  const float4* ga = reinterpret_cast<const float4*>(xa);  // row stride 32
  const float4* gb = reinterpret_cast<const float4*>(xb);

  for (int d0 = 0; d0 < 4; ++d0) {     // 4 chunks of 8 float4 (32 k)
    __syncthreads();   // previous chunk's reads done before overwrite
#pragma unroll
    for (int it = 0; it < 3; ++it) {
      int idx = tid + it * 256;        // 0..767
      int t = idx >> 3, k4 = idx & 7;  // row, logical slot
      int slot = (k4 + (t / 6)) & 7;   // rotated storage slot
      sa[t * 9 + slot] = ga[t * 32 + d0 * 8 + k4];
      sb[t * 9 + slot] = gb[t * 32 + d0 * 8 + k4];
    }
    __syncthreads();
#pragma unroll
    for (int k4 = 0; k4 < 8; ++k4) {
      float4 av4[6], bv4[6];
      const int sA = (k4 + ty) & 7;    // rotated slot for this lane's A rows
      const int sB = (k4 + tx) & 7;    // rotated slot for this lane's B rows
#pragma unroll
      for (int r = 0; r < 6; ++r)
        av4[r] = sa[(t0 + r) * 9 + sA];
#pragma unroll
      for (int c = 0; c < 6; ++c)
        bv4[c] = sb[(s0 + c) * 9 + sB];
#pragma unroll
      for (int r = 0; r < 6; ++r)
#pragma unroll
        for (int c = 0; c < 6; ++c) {
          acc[r][c] = fmaf(av4[r].x, bv4[c].x, acc[r][c]);
          acc[r][c] = fmaf(av4[r].y, bv4[c].y, acc[r][c]);
          acc[r][c] = fmaf(av4[r].z, bv4[c].z, acc[r][c]);
          acc[r][c] = fmaf(av4[r].w, bv4[c].w, acc[r][c]);
        }
    }
  }
  __syncthreads();
  const float rg2 = -LOG2E / gptr[0];
#pragma unroll
  for (int r = 0; r < 6; ++r) {
    float xr = xna[t0 + r];
#pragma unroll
    for (int c = 0; c < 6; ++c) {
      float cv = xr + xnb[s0 + c] - 2.0f * acc[r][c];   // exact ref C
      Cs[(t0 + r) * TT + (s0 + c)] = cv * rg2;          // pre-scaled, row-major
    }
  }
  __syncthreads();

  // write-out: diag-major, coalesced; wave wv handles diagonals d ≡ wv (mod 4)
  const size_t qb = (size_t)(w * NPAIR + pr) * CSZ;
  for (int d = wv; d < 2 * TT - 1; d += 4) {
    int s = d <= 95 ? 0 : d - 95;
    int len = d <= 95 ? d + 1 : 191 - d;
    int base = diag_base(d);
    if (lane < len) {
      int i = s + lane;
      Cd[qb + base + lane] = Cs[i * TT + (d - i)];
    }
    if (len > 64 && lane < len - 64) {
      int i = s + 64 + lane;
      Cd[qb + base + 64 + lane] = Cs[i * TT + (d - i)];
    }
  }
}

// K2: DP, TWO problems per wave (pr and pr+528). Per-problem op sequence is
// bit-identical to the r11 proven chain; interleaving doubles ILP.
#define ST_R2(d, qa0, qb0, qa1, qb1) do {                                \
    float cA0 = qa0, cB0 = qb0, cA1 = qa1, cB1 = qb1;                    \
    { int dn = (d) + 4;                                                  \
      if (dn <= 190) { int nb = diag_base(dn);                           \
        qa0 = cb0[nb + l]; qb0 = cb0[nb + 64 + l];                       \
        qa1 = cb1[nb + l]; qb1 = cb1[nb + 64 + l]; } }                   \
    float rA10 = __shfl(A1_0, lm1), rB10 = __shfl(B1_0, lm1);            \
    float rA11 = __shfl(A1_1, lm1), rB11 = __shfl(B1_1, lm1);            \
    float upA0 = l0 ? NEGI : rA10, dgA0 = l0 ? NEGI : pA1_0;             \
    float upB0 = l0 ? rA10 : rB10, dgB0 = l0 ? pA1_0 : pB1_0;            \
    float upA1 = l0 ? NEGI : rA11, dgA1 = l0 ? NEGI : pA1_1;             \
    float upB1 = l0 ? rA11 : rB11, dgB1 = l0 ? pA1_1 : pB1_1;            \
    float nA0 = cA0 + smin2(upA0, A1_0, dgA0);                           \
    float nB0 = cB0 + smin2(upB0, B1_0, dgB0);                           \
    float nA1 = cA1 + smin2(upA1, A1_1, dgA1);                           \
    float nB1 = cB1 + smin2(upB1, B1_1, dgB1);                           \
    A2_0 = A1_0; B2_0 = B1_0; A2_1 = A1_1; B2_1 = B1_1;                  \
    A1_0 = (l < (d) + 1) ? nA0 : NEGI;                                   \
    B1_0 = (64 + l < (d) + 1) ? nB0 : NEGI;                              \
    A1_1 = (l < (d) + 1) ? nA1 : NEGI;                                   \
    B1_1 = (64 + l < (d) + 1) ? nB1 : NEGI;                              \
    pA1_0 = rA10; pB1_0 = rB10; pA1_1 = rA11; pB1_1 = rB11;              \
  } while (0)

#define ST_RN2(d, qa0, qb0, qa1, qb1) do {  /* rising, B dead (d<=63) */ \
    float cA0 = qa0, cA1 = qa1;                                          \
    { int dn = (d) + 4;                                                  \
      if (dn <= 190) { int nb = diag_base(dn);                           \
        qa0 = cb0[nb + l]; qb0 = cb0[nb + 64 + l];                       \
        qa1 = cb1[nb + l]; qb1 = cb1[nb + 64 + l]; } }                   \
    float rA10 = __shfl(A1_0, lm1), rA11 = __shfl(A1_1, lm1);            \
    float upA0 = l0 ? NEGI : rA10, dgA0 = l0 ? NEGI : pA1_0;             \
    float upA1 = l0 ? NEGI : rA11, dgA1 = l0 ? NEGI : pA1_1;             \
    float nA0 = cA0 + smin2(upA0, A1_0, dgA0);                           \
    float nA1 = cA1 + smin2(upA1, A1_1, dgA1);                           \
    A2_0 = A1_0; A2_1 = A1_1;                                            \
    A1_0 = (l < (d) + 1) ? nA0 : NEGI;                                   \
    A1_1 = (l < (d) + 1) ? nA1 : NEGI;                                   \
    pA1_0 = rA10; pA1_1 = rA11;                                          \
  } while (0)

#define ST_F2(d, qa0, qb0, qa1, qb1) do {  /* falling, full */           \
    float cA0 = qa0, cB0 = qb0, cA1 = qa1, cB1 = qb1;                    \
    { int dn = (d) + 4;                                                  \
      if (dn <= 190) { int nb = diag_base(dn);                           \
        qa0 = cb0[nb + l]; qa1 = cb1[nb + l];                            \
        if (dn <= 128) { qb0 = cb0[nb + 64 + l]; qb1 = cb1[nb + 64 + l]; } } } \
    float rA10 = __shfl(A1_0, lp1), rB10 = __shfl(B1_0, lp1);            \
    float rA11 = __shfl(A1_1, lp1), rB11 = __shfl(B1_1, lp1);            \
    float lfA0 = l63 ? rB10 : rA10, dgA0 = l63 ? pB1_0 : pA1_0;          \
    float lfA1 = l63 ? rB11 : rA11, dgA1 = l63 ? pB1_1 : pA1_1;          \
    float nA0 = cA0 + smin2(A1_0, lfA0, dgA0);                           \
    float nB0 = cB0 + smin2(B1_0, rB10, pB1_0);                          \
    float nA1 = cA1 + smin2(A1_1, lfA1, dgA1);                           \
    float nB1 = cB1 + smin2(B1_1, rB11, pB1_1);                          \
    A1_0 = (l < 191 - (d)) ? nA0 : NEGI;                                 \
    B1_0 = (64 + l < 191 - (d)) ? nB0 : NEGI;                            \
    A1_1 = (l < 191 - (d)) ? nA1 : NEGI;                                 \
    B1_1 = (64 + l < 191 - (d)) ? nB1 : NEGI;                            \
    pA1_0 = rA10; pB1_0 = rB10; pA1_1 = rA11; pB1_1 = rB11;              \
  } while (0)

#define ST_FN2(d, qa0, qb0, qa1, qb1) do {  /* falling, B dead (d>=129) */ \
    float cA0 = qa0, cA1 = qa1;                                          \
    { int dn = (d) + 4;                                                  \
      if (dn <= 190) { int nb = diag_base(dn);                           \
        qa0 = cb0[nb + l]; qa1 = cb1[nb + l]; } }                        \
    float rA10 = __shfl(A1_0, lp1), rA11 = __shfl(A1_1, lp1);            \
    float lfA0 = l63 ? NEGI : rA10, dgA0 = l63 ? NEGI : pA1_0;           \
    float lfA1 = l63 ? NEGI : rA11, dgA1 = l63 ? NEGI : pA1_1;           \
    float nA0 = cA0 + smin2(A1_0, lfA0, dgA0);                           \
    float nA1 = cA1 + smin2(A1_1, lfA1, dgA1);                           \
    A1_0 = (l < 191 - (d)) ? nA0 : NEGI;                                 \
    A1_1 = (l < 191 - (d)) ? nA1 : NEGI;                                 \
    pA1_0 = rA10; pA1_1 = rA11;                                          \
  } while (0)

__global__ __launch_bounds__(64)
void dp_kernel(const float* __restrict__ Cd,
               const float* __restrict__ gptr,
               float* __restrict__ dtw) {
  const int pr = blockIdx.x;               // pair index; problems pr and pr+528
  const int l = threadIdx.x;
  const float gamma = gptr[0];
  const float rg2 = -LOG2E / gamma;
  const float NEGI = FINF * rg2;           // invalid cell in z''-domain
  const float* __restrict__ cb0 = Cd + (size_t)pr * CSZ;
  const float* __restrict__ cb1 = Cd + (size_t)(NPAIR + pr) * CSZ;
  const int lp1 = (l + 1) & 63, lm1 = (l + 63) & 63;
  const bool l0 = (l == 0), l63 = (l == 63);

  // prefetch queue: slot (d-1)&3; preload diagonals 1..4 (both problems)
  float q0A0, q0B0, q1A0, q1B0, q2A0, q2B0, q3A0, q3B0;
  float q0A1, q0B1, q1A1, q1B1, q2A1, q2B1, q3A1, q3B1;
  {
    int b1 = diag_base(1), b2 = diag_base(2), b3 = diag_base(3), b4 = diag_base(4);
    q0A0 = cb0[b1 + l]; q0B0 = cb0[b1 + 64 + l];
    q1A0 = cb0[b2 + l]; q1B0 = cb0[b2 + 64 + l];
    q2A0 = cb0[b3 + l]; q2B0 = cb0[b3 + 64 + l];
    q3A0 = cb0[b4 + l]; q3B0 = cb0[b4 + 64 + l];
    q0A1 = cb1[b1 + l]; q0B1 = cb1[b1 + 64 + l];
    q1A1 = cb1[b2 + l]; q1B1 = cb1[b2 + 64 + l];
    q2A1 = cb1[b3 + l]; q2B1 = cb1[b3 + 64 + l];
    q3A1 = cb1[b4 + l]; q3B1 = cb1[b4 + 64 + l];
  }

  // d=0 peel: r(0,0)'' = C''(0,0)
  float A1_0 = l0 ? cb0[0] : NEGI;
  float A1_1 = l0 ? cb1[0] : NEGI;
  float B1_0 = NEGI, A2_0 = NEGI, B2_0 = NEGI;
  float B1_1 = NEGI, A2_1 = NEGI, B2_1 = NEGI;
  float pA1_0 = NEGI, pB1_0 = NEGI;   // shadow: last iter's shfl(A1/B1)
  float pA1_1 = NEGI, pB1_1 = NEGI;

  // rising, B dead: d = 1..60 (15 groups), peel 61,62,63
  for (int g = 0; g < 15; ++g) {
    int d = 1 + g * 4;
    ST_RN2(d,     q0A0, q0B0, q0A1, q0B1);
    ST_RN2(d + 1, q1A0, q1B0, q1A1, q1B1);
    ST_RN2(d + 2, q2A0, q2B0, q2A1, q2B1);
    ST_RN2(d + 3, q3A0, q3B0, q3A1, q3B1);
  }
  ST_RN2(61, q0A0, q0B0, q0A1, q0B1);
  ST_RN2(62, q1A0, q1B0, q1A1, q1B1);
  ST_RN2(63, q2A0, q2B0, q2A1, q2B1);

  // rising, full: d = 64, 65..92 (7 groups), peel 93,94,95
  ST_R2(64, q3A0, q3B0, q3A1, q3B1);
  for (int g = 0; g < 7; ++g) {
    int d = 65 + g * 4;
    ST_R2(d,     q0A0, q0B0, q0A1, q0B1);
    ST_R2(d + 1, q1A0, q1B0, q1A1, q1B1);
    ST_R2(d + 2, q2A0, q2B0, q2A1, q2B1);
    ST_R2(d + 3, q3A0, q3B0, q3A1, q3B1);
  }
  ST_R2(93, q0A0, q0B0, q0A1, q0B1);
  ST_R2(94, q1A0, q1B0, q1A1, q1B1);
  ST_R2(95, q2A0, q2B0, q2A1, q2B1);

  // d = 96 boundary: offsets (0, +1, 0); consumes q3, prefetches 100
  {
    float cA0 = q3A0, cB0 = q3B0, cA1 = q3A1, cB1 = q3B1;
    int nb = diag_base(100);
    q3A0 = cb0[nb + l]; q3B0 = cb0[nb + 64 + l];
    q3A1 = cb1[nb + l]; q3B1 = cb1[nb + 64 + l];
    float rA10 = __shfl(A1_0, lp1), rB10 = __shfl(B1_0, lp1);
    float rA11 = __shfl(A1_1, lp1), rB11 = __shfl(B1_1, lp1);
    float lfA0 = l63 ? rB10 : rA10;
    float lfA1 = l63 ? rB11 : rA11;
    float nA0 = cA0 + smin2(A1_0, lfA0, A2_0);
    float nB0 = cB0 + smin2(B1_0, rB10, B2_0);
    float nA1 = cA1 + smin2(A1_1, lfA1, A2_1);
    float nB1 = cB1 + smin2(B1_1, rB11, B2_1);
    A1_0 = (l < 95) ? nA0 : NEGI;        // len = 95
    B1_0 = (64 + l < 95) ? nB0 : NEGI;
    A1_1 = (l < 95) ? nA1 : NEGI;
    B1_1 = (64 + l < 95) ? nB1 : NEGI;
    pA1_0 = rA10; pB1_0 = rB10; pA1_1 = rA11; pB1_1 = rB11;
  }

  // falling, full: d = 97..128 (8 groups)
  for (int g = 0; g < 8; ++g) {
    int d = 97 + g * 4;
    ST_F2(d,     q0A0, q0B0, q0A1, q0B1);
    ST_F2(d + 1, q1A0, q1B0, q1A1, q1B1);
    ST_F2(d + 2, q2A0, q2B0, q2A1, q2B1);
    ST_F2(d + 3, q3A0, q3B0, q3A1, q3B1);
  }
  // falling, B dead: d = 129..188 (15 groups), peel 189,190
  for (int g = 0; g < 15; ++g) {
    int d = 129 + g * 4;
    ST_FN2(d,     q0A0, q0B0, q0A1, q0B1);
    ST_FN2(d + 1, q1A0, q1B0, q1A1, q1B1);
    ST_FN2(d + 2, q2A0, q2B0, q2A1, q2B1);
    ST_FN2(d + 3, q3A0, q3B0, q3A1, q3B1);
  }
  ST_FN2(189, q0A0, q0B0, q0A1, q0B1);
  ST_FN2(190, q1A0, q1B0, q1A1, q1B1);

  // cell (95,95) = position 0 of diag 190 -> lane 0, A1
  if (l0) {
    int a, b;
    tri_decode(pr, a, b);
    float v0 = A1_0 * (-gamma * LN2);    // student (w=0)
    float v1 = A1_1 * (-gamma * LN2);    // teacher (w=1)
    dtw[a * BB + b] = v0;
    dtw[b * BB + a] = v0;
    dtw[NP + a * BB + b] = v1;
    dtw[NP + b * BB + a] = v1;
  }
}

// ---------------- Fallback fused kernel (round-3, proven) ----------------
__global__ __launch_bounds__(256)
void sdtw_fused_kernel(const float* __restrict__ xs,
                       const float* __restrict__ xt,
                       const float* __restrict__ xn,
                       const float* __restrict__ gptr,
                       float* __restrict__ dtw) {
  __shared__ __align__(16) float Cs[TT * TT];
  __shared__ float xna[TT];
  __shared__ float xnb[TT];

  const int pr = blockIdx.x;
  int a, b;
  tri_decode(pr, a, b);
  const int w = blockIdx.y;
  const float* x = w ? xt : xs;
  const float* xnw = xn + w * (BB * TT);
  const float* xa = x + (size_t)a * TT * DD;
  const float* xb = x + (size_t)b * TT * DD;
  const int tid = threadIdx.x;

  if (tid < TT) {
    xna[tid] = xnw[a * TT + tid];
    xnb[tid] = xnw[b * TT + tid];
  }
  constexpr int SROW = 36;
  float* xa_s = Cs;
  float* xb_s = Cs + TT * SROW;
  const int wv = tid >> 6;
  const int lane = tid & 63;
  const int tx = (lane & 7) + (wv & 1) * 8;
  const int ty = (lane >> 3) + (wv >> 1) * 8;
  const int t0 = ty * 6, s0 = tx * 6;
  float acc[6][6];
#pragma unroll
  for (int r = 0; r < 6; ++r)
#pragma unroll
    for (int c = 0; c < 6; ++c) acc[r][c] = 0.f;
  for (int d0 = 0; d0 < DD; d0 += 32) {
    __syncthreads();
    const float4* ga = reinterpret_cast<const float4*>(xa + d0);
    const float4* gb = reinterpret_cast<const float4*>(xb + d0);
    float4* sa = reinterpret_cast<float4*>(xa_s);
    float4* sb = reinterpret_cast<float4*>(xb_s);
#pragma unroll
    for (int it = 0; it < 3; ++it) {
      int idx = tid + it * 256;
      int t = idx >> 3, k4 = idx & 7;
      sa[t * (SROW / 4) + k4] = ga[t * (DD / 4) + k4];
      sb[t * (SROW / 4) + k4] = gb[t * (DD / 4) + k4];
    }
    __syncthreads();
#pragma unroll
    for (int k4 = 0; k4 < 8; ++k4) {
      float4 av4[6], bv4[6];
#pragma unroll
      for (int r = 0; r < 6; ++r)
        av4[r] = reinterpret_cast<const float4*>(xa_s + (t0 + r) * SROW)[k4];
#pragma unroll
      for (int c = 0; c < 6; ++c)
        bv4[c] = reinterpret_cast<const float4*>(xb_s + (s0 + c) * SROW)[k4];
#pragma unroll
      for (int r = 0; r < 6; ++r)
#pragma unroll
        for (int c = 0; c < 6; ++c) {
          acc[r][c] = fmaf(av4[r].x, bv4[c].x, acc[r][c]);
          acc[r][c] = fmaf(av4[r].y, bv4[c].y, acc[r][c]);
          acc[r][c] = fmaf(av4[r].z, bv4[c].z, acc[r][c]);
          acc[r][c] = fmaf(av4[r].w, bv4[c].w, acc[r][c]);
        }
    }
  }
  __syncthreads();
#pragma unroll
  for (int r = 0; r < 6; ++r) {
    float xr = xna[t0 + r];
#pragma unroll
    for (int c = 0; c < 6; ++c)
      Cs[(t0 + r) * TT + (s0 + c)] = xr + xnb[s0 + c] - 2.0f * acc[r][c];
  }
  __syncthreads();
  if (tid >= 64) return;

  const float gamma = gptr[0];
  const float rg = -1.0f / gamma;
  const int lm1 = (lane + 63) & 63;
  float A1 = FINF, B1 = FINF, A2 = FINF, B2 = FINF;
  for (int d = 0; d < 2 * TT - 1; ++d) {
    int jA = d - lane;
    bool vA = (jA >= 0) && (jA < TT);
    float cA = Cs[vA ? lane * TT + jA : 0];
    int iB = 64 + lane;
    int jB = d - iB;
    bool vB = (lane < 32) && (jB >= 0) && (jB < TT);
    float cB = Cs[vB ? iB * TT + jB : 0];
    float rA1 = __shfl(A1, lm1);
    float rB1 = __shfl(B1, lm1);
    float rA2 = __shfl(A2, lm1);
    float rB2 = __shfl(B2, lm1);
    const bool l0 = (lane == 0);
    float upA = l0 ? FINF : rA1;
    float dgA = l0 ? FINF : rA2;
    float upB = l0 ? rA1 : rB1;
    float dgB = l0 ? rA2 : rB2;
    float z0 = upA * rg, z1 = A1 * rg, z2 = dgA * rg;
    float m = fmaxf(fmaxf(z0, z1), z2);
    float s = expf(z0 - m) + expf(z1 - m) + expf(z2 - m);
    float sminA = -gamma * (m + logf(s));
    if (d == 0) sminA = 0.f;
    float y0 = upB * rg, y1 = B1 * rg, y2 = dgB * rg;
    float mb = fmaxf(fmaxf(y0, y1), y2);
    float sb2 = expf(y0 - mb) + expf(y1 - mb) + expf(y2 - mb);
    float sminB = -gamma * (mb + logf(sb2));
    float nA = vA ? cA + sminA : FINF;
    float nB = vB ? cB + sminB : FINF;
    A2 = A1; B2 = B1; A1 = nA; B1 = nB;
  }
  if (lane == 31) {
    float v = B1;
    dtw[w * NP + a * BB + b] = v;
    dtw[w * NP + b * BB + a] = v;
  }
}

// K3: means + normalized smooth-L1 (single block).
__global__ void reduce_kernel(const float* __restrict__ dtw,
                              float* __restrict__ out) {
  __shared__ double sh[256];
  const int tid = threadIdx.x;
  double ss = 0, st = 0;
  for (int k = tid; k < NP; k += 256) {
    ss += (double)dtw[k];
    st += (double)dtw[NP + k];
  }
  sh[tid] = ss; __syncthreads();
  for (int o = 128; o > 0; o >>= 1) { if (tid < o) sh[tid] += sh[tid + o]; __syncthreads(); }
  double sum_s = sh[0]; __syncthreads();
  sh[tid] = st; __syncthreads();
  for (int o = 128; o > 0; o >>= 1) { if (tid < o) sh[tid] += sh[tid + o]; __syncthreads(); }
  double sum_t = sh[0]; __syncthreads();

  float mean_s = (float)(sum_s / NP);
  float mean_t = (float)(sum_t / NP);

  double acc = 0;
  for (int k = tid; k < NP; k += 256) {
    float pred = dtw[k] / mean_s;
    float targ = dtw[NP + k] / mean_t;
    float d = pred - targ;
    float ad = fabsf(d);
    float v = ad < 1.f ? 0.5f * d * d : ad - 0.5f;
    acc += (double)v;
  }
  sh[tid] = acc; __syncthreads();
  for (int o = 128; o > 0; o >>= 1) { if (tid < o) sh[tid] += sh[tid + o]; __syncthreads(); }
  if (tid == 0) out[0] = (float)(sh[0] / NP);
}

extern "C" void kernel_launch(void* const* d_in, const int* in_sizes, int n_in,
                              void* d_out, int out_size, void* d_ws, size_t ws_size,
                              hipStream_t stream) {
  const float* student = (const float*)d_in[0];
  const float* teacher = (const float*)d_in[1];
  const float* gamma   = (const float*)d_in[2];
  float* ws = (float*)d_ws;

  const size_t cd_floats = (size_t)NPROB * CSZ;              // 9,732,096
  const size_t need = (cd_floats + 2 * NP + 2 * BB * TT) * sizeof(float);

  if (ws_size >= need) {
    float* Cd  = ws;
    float* dtw = ws + cd_floats;
    float* xnb = dtw + 2 * NP;
    xn_kernel<<<24, 256, 0, stream>>>(student, teacher, xnb);
    csq_kernel<<<dim3(NPAIR, 2), 256, 0, stream>>>(student, teacher, xnb, gamma, Cd);
    dp_kernel<<<NPAIR, 64, 0, stream>>>(Cd, gamma, dtw);
    reduce_kernel<<<1, 256, 0, stream>>>(dtw, (float*)d_out);
  } else {
    float* dtw = ws;
    float* xnb = ws + 2 * NP;
    xn_kernel<<<24, 256, 0, stream>>>(student, teacher, xnb);
    sdtw_fused_kernel<<<dim3(NPAIR, 2), 256, 0, stream>>>(student, teacher, xnb, gamma, dtw);
    reduce_kernel<<<1, 256, 0, stream>>>(dtw, (float*)d_out);
  }
}